// Round 11
// baseline (175.698 us; speedup 1.0000x reference)
//
#include <hip/hip_runtime.h>

// ---------------------------------------------------------------------------
// MHA forward: out = proj_o( softmax(QK^T/sqrt(dk)) V ),  Q/K/V = x @ W^T + b
// B=4 S=2048 D=1024 H=16 dk=64.  bf16 MFMA pipeline, fp32 accum.
// Round 11: T15 cross-tile pipeline on the r10 base (q=64/wave, 2 blocks/CU,
// 256-VGPR budget — r7/r8 failed under a 128-VGPR cap). PV(t-1) deferred into
// tile-t's barrier window so its 32 independent MFMAs fill the latency bubbles
// of QK(t)->exp2->cvt chains (attn is latency-bound: all pipes <40%).
// V triple-buffered (40KB LDS), named paA/paB ping-pong, r8's verified
// control flow. GEMMs / cvt unchanged.
// ---------------------------------------------------------------------------

typedef unsigned short u16;
typedef unsigned int u32;
typedef __attribute__((ext_vector_type(8))) short bf16x8;   // 8 bf16 (4 VGPR)
typedef __attribute__((ext_vector_type(4))) float f32x4;    // MFMA C/D frag
typedef __attribute__((ext_vector_type(4))) unsigned short u16x4;
typedef __attribute__((ext_vector_type(8))) unsigned short u16x8;

#define SEQ    2048
#define DMODEL 1024
#define NHEAD  16
#define DK     64
#define BATCH  4
#define MROWS  (BATCH * SEQ)   // 8192
#define LCF    0.18033688011112042f   // (1/sqrt(64)) * log2(e)

__device__ __forceinline__ u16 f2bf(float f) {   // RNE fp32 -> bf16
  unsigned int u = __float_as_uint(f);
  u += 0x7fffu + ((u >> 16) & 1u);
  return (u16)(u >> 16);
}

__device__ __forceinline__ void gload_lds16(const void* g, void* l) {
  __builtin_amdgcn_global_load_lds((const __attribute__((address_space(1))) void*)g,
                                   (__attribute__((address_space(3))) void*)l,
                                   16, 0, 0);
}

// ---------------- fp32 -> bf16 conversion (x + 4 weights, one launch) -------
__global__ __launch_bounds__(256) void cvt_all(const float* __restrict__ x,
                                               const float* __restrict__ w0,
                                               const float* __restrict__ w1,
                                               const float* __restrict__ w2,
                                               const float* __restrict__ w3,
                                               u16* xb, u16* o0, u16* o1, u16* o2, u16* o3) {
  const int NX4 = MROWS * DMODEL / 4;
  int i = blockIdx.x * 256 + threadIdx.x;
  const float* src; u16* dst; int off;
  if (i < NX4) { src = x; dst = xb; off = i; }
  else {
    int j = i - NX4;
    int wi = j >> 18; off = j & 0x3FFFF;
    src = wi == 0 ? w0 : wi == 1 ? w1 : wi == 2 ? w2 : w3;
    dst = wi == 0 ? o0 : wi == 1 ? o1 : wi == 2 ? o2 : o3;
  }
  float4 v = ((const float4*)src)[off];
  u16x4 o;
  o.x = f2bf(v.x); o.y = f2bf(v.y); o.z = f2bf(v.z); o.w = f2bf(v.w);
  ((u16x4*)dst)[off] = o;
}

// ---------------- GEMM core (128x128 tile, BK=64, swizzled LDS) -------------
template <int OUT_F32>
__device__ __forceinline__ void gemm_body(const u16* __restrict__ A,
                                          const u16* __restrict__ Bw,
                                          const float* __restrict__ bias,
                                          void* __restrict__ outp,
                                          int bm, int bn, int M, int N, int K,
                                          float scale, int vt_mode,
                                          u16* As, u16* Bs) {
  const int t = threadIdx.x, w = t >> 6, l = t & 63;
  const int wr = (w >> 1) * 64, wc = (w & 1) * 64;
  const int lrow = l & 15, kgrp = l >> 4;
  const int r_in = l >> 3;
  const int c_in = ((l & 7) ^ r_in) * 8;
  const int sw = lrow & 7;

  f32x4 acc[4][4] = {};

  for (int kt = 0; kt < K; kt += 64) {
#pragma unroll
    for (int it = 0; it < 4; ++it) {
      const int chunk = w * 4 + it;
      const int row = chunk * 8 + r_in;
      gload_lds16(A  + (size_t)(bm * 128 + row) * K + kt + c_in, (char*)As + chunk * 1024);
      gload_lds16(Bw + (size_t)(bn * 128 + row) * K + kt + c_in, (char*)Bs + chunk * 1024);
    }
    __syncthreads();
#pragma unroll
    for (int kc = 0; kc < 2; ++kc) {
      bf16x8 af[4], bfr[4];
      const int slot = (kc * 4 + kgrp) ^ sw;
#pragma unroll
      for (int m = 0; m < 4; ++m)
        af[m] = *(const bf16x8*)&As[(wr + m * 16 + lrow) * 64 + slot * 8];
#pragma unroll
      for (int n = 0; n < 4; ++n)
        bfr[n] = *(const bf16x8*)&Bs[(wc + n * 16 + lrow) * 64 + slot * 8];
#pragma unroll
      for (int m = 0; m < 4; ++m)
#pragma unroll
        for (int n = 0; n < 4; ++n)
          acc[m][n] = __builtin_amdgcn_mfma_f32_16x16x32_bf16(af[m], bfr[n], acc[m][n], 0, 0, 0);
    }
    __syncthreads();
  }

  const int cr0 = bm * 128 + wr, cc0 = bn * 128 + wc;
  if (!OUT_F32 && vt_mode) {
    const int s0 = (bm & 15) * 128 + wr + kgrp * 4;
    u16* vtp = (u16*)outp + (size_t)(bm >> 4) * 1024 * 2048;
#pragma unroll
    for (int n = 0; n < 4; ++n) {
      const int col = cc0 + n * 16 + lrow;
      const float bv = bias[col];
#pragma unroll
      for (int m = 0; m < 4; ++m) {
        u16x4 pk;
#pragma unroll
        for (int r = 0; r < 4; ++r) pk[r] = f2bf(acc[m][n][r] + bv);
        *(u16x4*)&vtp[(size_t)col * 2048 + s0 + m * 16] = pk;
      }
    }
    return;
  }
#pragma unroll
  for (int n = 0; n < 4; ++n) {
    const int col = cc0 + n * 16 + lrow;
    const float bv = bias[col];
#pragma unroll
    for (int m = 0; m < 4; ++m) {
#pragma unroll
      for (int r = 0; r < 4; ++r) {
        const int row = cr0 + m * 16 + kgrp * 4 + r;
        const float v = (acc[m][n][r] + bv) * scale;
        if (OUT_F32) ((float*)outp)[(size_t)row * N + col] = v;
        else         ((u16*)outp)[(size_t)row * N + col] = f2bf(v);
      }
    }
  }
}

// out-projection: 1-D grid 512; XCD x owns bm in [8x, 8x+8)
__global__ __launch_bounds__(256) void gemm_bt_f32(const u16* __restrict__ A,
                                                   const u16* __restrict__ Bw,
                                                   const float* __restrict__ bias,
                                                   float* __restrict__ outp) {
  __shared__ u16 As[128 * 64];
  __shared__ u16 Bs[128 * 64];
  const int wg = blockIdx.x;
  const int xcd = wg & 7, local = wg >> 3;
  const int lm = local & 7, bn = local >> 3;
  const int bm = xcd * 8 + lm;
  gemm_body<1>(A, Bw, bias, outp, bm, bn, MROWS, DMODEL, DMODEL, 1.0f, 0, As, Bs);
}

// merged Q/K/V projection: 1-D grid 1536; XCD x owns bm in [8x, 8x+8).
__global__ __launch_bounds__(256) void gemm_qkv(const u16* __restrict__ A,
                                                const u16* __restrict__ W0,
                                                const u16* __restrict__ W1,
                                                const u16* __restrict__ W2,
                                                const float* __restrict__ b0,
                                                const float* __restrict__ b1,
                                                const float* __restrict__ b2,
                                                u16* o0, u16* o1, u16* vt) {
  __shared__ u16 As[128 * 64];
  __shared__ u16 Bs[128 * 64];
  const int wg = blockIdx.x;
  const int xcd = wg & 7, local = wg >> 3;
  const int lm = local & 7, lnsel = local >> 3;
  const int bm = xcd * 8 + lm;
  const int sel = lnsel >> 3, bn = lnsel & 7;
  const u16* Bw = sel == 0 ? W0 : sel == 1 ? W1 : W2;
  const float* bias = sel == 0 ? b0 : sel == 1 ? b1 : b2;
  u16* outp = sel == 0 ? o0 : sel == 1 ? o1 : vt;
  const float scale = sel == 0 ? LCF : 1.0f;
  gemm_body<0>(A, Bw, bias, outp, bm, bn, MROWS, DMODEL, DMODEL, scale,
               sel == 2 ? 1 : 0, As, Bs);
}

// ---------------- flash attention (r10 base + T15 cross-tile pipeline) -------
// grid 512 (XCD-swizzled), 256 thr = 4 waves; wave: 64 q (4 rg) x 64 kv/iter.
// Swapped QK^T, staging-permuted K (PV A-frag = register regroup), no-max
// softmax (|score*log2e| <= ~6 << 126). K dbuf, V triple-buf; PV(t-1) runs in
// tile-t's window (independent MFMAs fill QK/exp2/cvt latency bubbles).
__global__ __launch_bounds__(256, 2) void attn_kernel(const u16* __restrict__ Qg,
                                                      const u16* __restrict__ Kg,
                                                      const u16* __restrict__ Vt,
                                                      u16* __restrict__ Og) {
  __shared__ u16 Ks[2][64 * 64];     // [key-pos][d], 8-slot XOR swizzle
  __shared__ u16 Vs[3][64 * 64];     // [d][key], 8-slot XOR swizzle

  const int t = threadIdx.x, w = t >> 6, l = t & 63;
  const int lrow = l & 15, kgrp = l >> 4;
  const int sw = lrow & 7;

  const int id = blockIdx.x;                      // 512 blocks
  const int swzid = (id & 7) * 64 + (id >> 3);    // XCD x -> 64 contiguous ids
  const int qt = swzid & 7, bh = swzid >> 3;      // bh in [8x, 8x+8)
  const int b = bh >> 4, h = bh & 15;
  const size_t base  = (size_t)b * SEQ * DMODEL + h * DK;
  const size_t vbase = (size_t)bh * DK * SEQ;
  const int r_in = l >> 3;
  const int c_in = ((l & 7) ^ r_in) * 8;

  // K staging row permutation (per-thread constants)
  int kro[2];
#pragma unroll
  for (int it = 0; it < 2; ++it) {
    const int p = (w * 2 + it) * 8 + r_in;
    const int n_ = p >> 4, g_ = (p >> 2) & 3, rr = p & 3;
    kro[it] = (n_ >> 1) * 32 + g_ * 8 + (n_ & 1) * 4 + rr;
  }

  // Q fragments (B-operand): col=q=lrow, k-octet d=kgrp*8 (+32); pre-scaled
  const int qr = qt * 256 + w * 64;
  bf16x8 aq[4][2];
#pragma unroll
  for (int rg = 0; rg < 4; ++rg) {
    const u16* qp = Qg + base + (size_t)(qr + rg * 16 + lrow) * DMODEL + kgrp * 8;
    aq[rg][0] = *(const bf16x8*)qp;
    aq[rg][1] = *(const bf16x8*)(qp + 32);
  }

  f32x4 o_acc[4][4] = {};
  float lsum[4] = {};
  bf16x8 paA[4][2], paB[4][2];
  const int slot0 = (kgrp ^ sw) * 8;        // kc=0 fragment slot
  const int slot1 = ((4 + kgrp) ^ sw) * 8;  // kc=1 fragment slot

#define STAGE(kt_, kb_, vb_)                                                    \
  {                                                                             \
    const int k0_ = (kt_) * 64;                                                 \
    _Pragma("unroll")                                                           \
    for (int it = 0; it < 2; ++it) {                                            \
      const int chunk = w * 2 + it;                                             \
      const int r = chunk * 8 + r_in;                                           \
      gload_lds16(Kg + base + (size_t)(k0_ + kro[it]) * DMODEL + c_in,          \
                  (char*)&Ks[kb_][0] + chunk * 1024);                           \
      gload_lds16(Vt + vbase + (size_t)r * SEQ + k0_ + c_in,                    \
                  (char*)&Vs[vb_][0] + chunk * 1024);                           \
    }                                                                           \
  }

// QK^T + softmax for one tile -> PA (K frags loaded once, shared by 4 rg)
#define QKSM_BLOCK(KB, PA)                                                      \
  {                                                                             \
    bf16x8 kf0[4], kf1[4];                                                      \
    _Pragma("unroll")                                                           \
    for (int n = 0; n < 4; ++n) {                                               \
      kf0[n] = *(const bf16x8*)&Ks[KB][(n * 16 + lrow) * 64 + slot0];           \
      kf1[n] = *(const bf16x8*)&Ks[KB][(n * 16 + lrow) * 64 + slot1];           \
    }                                                                           \
    _Pragma("unroll")                                                           \
    for (int rg = 0; rg < 4; ++rg) {                                            \
      f32x4 sc[4] = {};                                                         \
      __builtin_amdgcn_s_setprio(1);                                            \
      _Pragma("unroll")                                                         \
      for (int n = 0; n < 4; ++n)                                               \
        sc[n] = __builtin_amdgcn_mfma_f32_16x16x32_bf16(kf0[n], aq[rg][0], sc[n], 0, 0, 0); \
      _Pragma("unroll")                                                         \
      for (int n = 0; n < 4; ++n)                                               \
        sc[n] = __builtin_amdgcn_mfma_f32_16x16x32_bf16(kf1[n], aq[rg][1], sc[n], 0, 0, 0); \
      __builtin_amdgcn_s_setprio(0);                                            \
      u32 pk[4][2];                                                             \
      float lp = 0.0f;                                                          \
      _Pragma("unroll")                                                         \
      for (int n = 0; n < 4; ++n) {                                             \
        const float p0 = __builtin_amdgcn_exp2f(sc[n][0]);                      \
        const float p1 = __builtin_amdgcn_exp2f(sc[n][1]);                      \
        const float p2 = __builtin_amdgcn_exp2f(sc[n][2]);                      \
        const float p3 = __builtin_amdgcn_exp2f(sc[n][3]);                      \
        lp += (p0 + p1) + (p2 + p3);                                            \
        asm("v_cvt_pk_bf16_f32 %0, %1, %2" : "=v"(pk[n][0]) : "v"(p0), "v"(p1));\
        asm("v_cvt_pk_bf16_f32 %0, %1, %2" : "=v"(pk[n][1]) : "v"(p2), "v"(p3));\
      }                                                                         \
      lsum[rg] += lp;                                                           \
      union { u32 u[4]; bf16x8 v; } f0, f1;                                     \
      f0.u[0] = pk[0][0]; f0.u[1] = pk[0][1]; f0.u[2] = pk[1][0]; f0.u[3] = pk[1][1]; \
      f1.u[0] = pk[2][0]; f1.u[1] = pk[2][1]; f1.u[2] = pk[3][0]; f1.u[3] = pk[3][1]; \
      PA[rg][0] = f0.v;                                                         \
      PA[rg][1] = f1.v;                                                         \
    }                                                                           \
  }

#define PV_BLOCK(PA, VB)                                                        \
  {                                                                             \
    bf16x8 vf0[4], vf1[4];                                                      \
    _Pragma("unroll")                                                           \
    for (int n = 0; n < 4; ++n) {                                               \
      vf0[n] = *(const bf16x8*)&Vs[VB][(n * 16 + lrow) * 64 + slot0];           \
      vf1[n] = *(const bf16x8*)&Vs[VB][(n * 16 + lrow) * 64 + slot1];           \
    }                                                                           \
    __builtin_amdgcn_s_setprio(1);                                              \
    _Pragma("unroll")                                                           \
    for (int rg = 0; rg < 4; ++rg) {                                            \
      _Pragma("unroll")                                                         \
      for (int n = 0; n < 4; ++n)                                               \
        o_acc[rg][n] = __builtin_amdgcn_mfma_f32_16x16x32_bf16(PA[rg][0], vf0[n], o_acc[rg][n], 0, 0, 0); \
      _Pragma("unroll")                                                         \
      for (int n = 0; n < 4; ++n)                                               \
        o_acc[rg][n] = __builtin_amdgcn_mfma_f32_16x16x32_bf16(PA[rg][1], vf1[n], o_acc[rg][n], 0, 0, 0); \
    }                                                                           \
    __builtin_amdgcn_s_setprio(0);                                              \
  }

  // prologue: tile 0 (K0,V0); stage tile 1 (K1,V1); QK+SM(0) -> paA
  STAGE(0, 0, 0);
  __syncthreads();
  STAGE(1, 1, 1);
  QKSM_BLOCK(0, paA);

  int vi_w = 2, vi_r = 0;                  // V write/read rotation (mod 3)
  // windows for tiles 1..30 (2 per loop); PV(t-1) overlaps QK/SM(t)
#pragma unroll 1
  for (int jj = 0; jj < 15; ++jj) {
    __syncthreads();                       // stage(tA) done (tA = 1+2jj)
    STAGE(2 + 2 * jj, 0, vi_w);            // tA+1 even -> K buf 0
    vi_w = (vi_w == 2) ? 0 : vi_w + 1;
    QKSM_BLOCK(1, paB);                    // tile tA (odd -> K buf 1)
    PV_BLOCK(paA, vi_r);                   // tile tA-1
    vi_r = (vi_r == 2) ? 0 : vi_r + 1;

    __syncthreads();                       // stage(tA+1) done
    STAGE(3 + 2 * jj, 1, vi_w);            // tA+2 odd -> K buf 1
    vi_w = (vi_w == 2) ? 0 : vi_w + 1;
    QKSM_BLOCK(0, paA);                    // tile tA+1 (even -> K buf 0)
    PV_BLOCK(paB, vi_r);                   // tile tA
    vi_r = (vi_r == 2) ? 0 : vi_r + 1;
  }
  // epilogue: tile 31 (odd -> K buf 1, V buf 31%3 = 1)
  __syncthreads();                         // stage(31) done
  QKSM_BLOCK(1, paB);                      // tile 31
  PV_BLOCK(paA, vi_r);                     // tile 30 (V buf 0)
  vi_r = (vi_r == 2) ? 0 : vi_r + 1;
  PV_BLOCK(paB, vi_r);                     // tile 31 (V buf 1)

#undef STAGE
#undef QKSM_BLOCK
#undef PV_BLOCK

  // epilogue: complete row sums, write O
#pragma unroll
  for (int rg = 0; rg < 4; ++rg) {
    float Lq = lsum[rg];
    Lq += __shfl_xor(Lq, 16);
    Lq += __shfl_xor(Lq, 32);                 // full sum for q = lrow
#pragma unroll
    for (int r = 0; r < 4; ++r) {
      const float inv = 1.0f / __shfl(Lq, kgrp * 4 + r);
      const int row = qr + rg * 16 + kgrp * 4 + r;
#pragma unroll
      for (int n = 0; n < 4; ++n)
        Og[base + (size_t)row * DMODEL + n * 16 + lrow] = f2bf(o_acc[rg][n][r] * inv);
    }
  }
}

// ---------------------------------------------------------------------------
extern "C" void kernel_launch(void* const* d_in, const int* in_sizes, int n_in,
                              void* d_out, int out_size, void* d_ws, size_t ws_size,
                              hipStream_t stream) {
  const float* x  = (const float*)d_in[0];
  const float* Wq = (const float*)d_in[1];
  const float* bq = (const float*)d_in[2];
  const float* Wk = (const float*)d_in[3];
  const float* bk = (const float*)d_in[4];
  const float* Wv = (const float*)d_in[5];
  const float* bv = (const float*)d_in[6];
  const float* Wo = (const float*)d_in[7];
  const float* bo = (const float*)d_in[8];
  float* out = (float*)d_out;

  const size_t XB   = (size_t)MROWS * DMODEL * 2;   // 16 MiB
  const size_t WB   = (size_t)DMODEL * DMODEL * 2;  // 2 MiB
  const size_t NEED = XB * 5 + WB * 4;
  if (ws_size < NEED) return;

  char* ws = (char*)d_ws;
  u16* xb  = (u16*)(ws);
  u16* wqb = (u16*)(ws + XB);
  u16* wkb = (u16*)(ws + XB + WB);
  u16* wvb = (u16*)(ws + XB + 2 * WB);
  u16* wob = (u16*)(ws + XB + 3 * WB);
  u16* qb  = (u16*)(ws + XB + 4 * WB);
  u16* kb  = (u16*)(ws + 2 * XB + 4 * WB);
  u16* vt  = (u16*)(ws + 3 * XB + 4 * WB);  // V^T [B,H,dk,S]
  u16* ab  = (u16*)(ws + 4 * XB + 4 * WB);

  const int NCVT = (MROWS * DMODEL / 4) + DMODEL * DMODEL;
  cvt_all<<<NCVT / 256, 256, 0, stream>>>(x, Wq, Wk, Wv, Wo, xb, wqb, wkb, wvb, wob);

  gemm_qkv<<<dim3(1536), 256, 0, stream>>>(xb, wqb, wkb, wvb,
                                           bq, bk, bv, qb, kb, vt);

  attn_kernel<<<dim3(512), 256, 0, stream>>>(qb, kb, vt, ab);

  gemm_bt_f32<<<dim3(512), 256, 0, stream>>>(ab, wob, bo, out);
}

// Round 12
// 173.546 us; speedup vs baseline: 1.0124x; 1.0124x over previous
//
#include <hip/hip_runtime.h>

// ---------------------------------------------------------------------------
// MHA forward: out = proj_o( softmax(QK^T/sqrt(dk)) V ),  Q/K/V = x @ W^T + b
// B=4 S=2048 D=1024 H=16 dk=64.  bf16 MFMA pipeline, fp32 accum.
// Round 12: REVERT to round-10 (best verified: 173.7 us). T15 rejected 3x
// (r7/r8/r11) — cross-tile PV deferral never recovers its register/occupancy
// cost on this structure; cross-block wave overlap (4 blocks/CU) already
// provides the MFMA||VALU co-issue. attn: q=64/wave, swapped QK^T,
// staging-permuted K (PV A-frag = register regroup), no-max softmax
// (|score*log2e| <= ~6 << 126: exp2 overflow-safe; end-normalize == exact
// softmax), K/V dbuf, 1 barrier/iter. GEMMs: 128x128 m97-structure with
// global_load_lds(16B), XOR-swizzled LDS, XCD-aware block remap; V-projection
// writes V^T directly.
// ---------------------------------------------------------------------------

typedef unsigned short u16;
typedef unsigned int u32;
typedef __attribute__((ext_vector_type(8))) short bf16x8;   // 8 bf16 (4 VGPR)
typedef __attribute__((ext_vector_type(4))) float f32x4;    // MFMA C/D frag
typedef __attribute__((ext_vector_type(4))) unsigned short u16x4;
typedef __attribute__((ext_vector_type(8))) unsigned short u16x8;

#define SEQ    2048
#define DMODEL 1024
#define NHEAD  16
#define DK     64
#define BATCH  4
#define MROWS  (BATCH * SEQ)   // 8192
#define LCF    0.18033688011112042f   // (1/sqrt(64)) * log2(e)

__device__ __forceinline__ u16 f2bf(float f) {   // RNE fp32 -> bf16
  unsigned int u = __float_as_uint(f);
  u += 0x7fffu + ((u >> 16) & 1u);
  return (u16)(u >> 16);
}

__device__ __forceinline__ void gload_lds16(const void* g, void* l) {
  __builtin_amdgcn_global_load_lds((const __attribute__((address_space(1))) void*)g,
                                   (__attribute__((address_space(3))) void*)l,
                                   16, 0, 0);
}

// ---------------- fp32 -> bf16 conversion (x + 4 weights, one launch) -------
__global__ __launch_bounds__(256) void cvt_all(const float* __restrict__ x,
                                               const float* __restrict__ w0,
                                               const float* __restrict__ w1,
                                               const float* __restrict__ w2,
                                               const float* __restrict__ w3,
                                               u16* xb, u16* o0, u16* o1, u16* o2, u16* o3) {
  const int NX4 = MROWS * DMODEL / 4;
  int i = blockIdx.x * 256 + threadIdx.x;
  const float* src; u16* dst; int off;
  if (i < NX4) { src = x; dst = xb; off = i; }
  else {
    int j = i - NX4;
    int wi = j >> 18; off = j & 0x3FFFF;
    src = wi == 0 ? w0 : wi == 1 ? w1 : wi == 2 ? w2 : w3;
    dst = wi == 0 ? o0 : wi == 1 ? o1 : wi == 2 ? o2 : o3;
  }
  float4 v = ((const float4*)src)[off];
  u16x4 o;
  o.x = f2bf(v.x); o.y = f2bf(v.y); o.z = f2bf(v.z); o.w = f2bf(v.w);
  ((u16x4*)dst)[off] = o;
}

// ---------------- GEMM core (128x128 tile, BK=64, swizzled LDS) -------------
template <int OUT_F32>
__device__ __forceinline__ void gemm_body(const u16* __restrict__ A,
                                          const u16* __restrict__ Bw,
                                          const float* __restrict__ bias,
                                          void* __restrict__ outp,
                                          int bm, int bn, int M, int N, int K,
                                          float scale, int vt_mode,
                                          u16* As, u16* Bs) {
  const int t = threadIdx.x, w = t >> 6, l = t & 63;
  const int wr = (w >> 1) * 64, wc = (w & 1) * 64;
  const int lrow = l & 15, kgrp = l >> 4;
  const int r_in = l >> 3;
  const int c_in = ((l & 7) ^ r_in) * 8;
  const int sw = lrow & 7;

  f32x4 acc[4][4] = {};

  for (int kt = 0; kt < K; kt += 64) {
#pragma unroll
    for (int it = 0; it < 4; ++it) {
      const int chunk = w * 4 + it;
      const int row = chunk * 8 + r_in;
      gload_lds16(A  + (size_t)(bm * 128 + row) * K + kt + c_in, (char*)As + chunk * 1024);
      gload_lds16(Bw + (size_t)(bn * 128 + row) * K + kt + c_in, (char*)Bs + chunk * 1024);
    }
    __syncthreads();
#pragma unroll
    for (int kc = 0; kc < 2; ++kc) {
      bf16x8 af[4], bfr[4];
      const int slot = (kc * 4 + kgrp) ^ sw;
#pragma unroll
      for (int m = 0; m < 4; ++m)
        af[m] = *(const bf16x8*)&As[(wr + m * 16 + lrow) * 64 + slot * 8];
#pragma unroll
      for (int n = 0; n < 4; ++n)
        bfr[n] = *(const bf16x8*)&Bs[(wc + n * 16 + lrow) * 64 + slot * 8];
#pragma unroll
      for (int m = 0; m < 4; ++m)
#pragma unroll
        for (int n = 0; n < 4; ++n)
          acc[m][n] = __builtin_amdgcn_mfma_f32_16x16x32_bf16(af[m], bfr[n], acc[m][n], 0, 0, 0);
    }
    __syncthreads();
  }

  const int cr0 = bm * 128 + wr, cc0 = bn * 128 + wc;
  if (!OUT_F32 && vt_mode) {
    const int s0 = (bm & 15) * 128 + wr + kgrp * 4;
    u16* vtp = (u16*)outp + (size_t)(bm >> 4) * 1024 * 2048;
#pragma unroll
    for (int n = 0; n < 4; ++n) {
      const int col = cc0 + n * 16 + lrow;
      const float bv = bias[col];
#pragma unroll
      for (int m = 0; m < 4; ++m) {
        u16x4 pk;
#pragma unroll
        for (int r = 0; r < 4; ++r) pk[r] = f2bf(acc[m][n][r] + bv);
        *(u16x4*)&vtp[(size_t)col * 2048 + s0 + m * 16] = pk;
      }
    }
    return;
  }
#pragma unroll
  for (int n = 0; n < 4; ++n) {
    const int col = cc0 + n * 16 + lrow;
    const float bv = bias[col];
#pragma unroll
    for (int m = 0; m < 4; ++m) {
#pragma unroll
      for (int r = 0; r < 4; ++r) {
        const int row = cr0 + m * 16 + kgrp * 4 + r;
        const float v = (acc[m][n][r] + bv) * scale;
        if (OUT_F32) ((float*)outp)[(size_t)row * N + col] = v;
        else         ((u16*)outp)[(size_t)row * N + col] = f2bf(v);
      }
    }
  }
}

// out-projection: 1-D grid 512; XCD x owns bm in [8x, 8x+8)
__global__ __launch_bounds__(256) void gemm_bt_f32(const u16* __restrict__ A,
                                                   const u16* __restrict__ Bw,
                                                   const float* __restrict__ bias,
                                                   float* __restrict__ outp) {
  __shared__ u16 As[128 * 64];
  __shared__ u16 Bs[128 * 64];
  const int wg = blockIdx.x;
  const int xcd = wg & 7, local = wg >> 3;
  const int lm = local & 7, bn = local >> 3;
  const int bm = xcd * 8 + lm;
  gemm_body<1>(A, Bw, bias, outp, bm, bn, MROWS, DMODEL, DMODEL, 1.0f, 0, As, Bs);
}

// merged Q/K/V projection: 1-D grid 1536; XCD x owns bm in [8x, 8x+8).
__global__ __launch_bounds__(256) void gemm_qkv(const u16* __restrict__ A,
                                                const u16* __restrict__ W0,
                                                const u16* __restrict__ W1,
                                                const u16* __restrict__ W2,
                                                const float* __restrict__ b0,
                                                const float* __restrict__ b1,
                                                const float* __restrict__ b2,
                                                u16* o0, u16* o1, u16* vt) {
  __shared__ u16 As[128 * 64];
  __shared__ u16 Bs[128 * 64];
  const int wg = blockIdx.x;
  const int xcd = wg & 7, local = wg >> 3;
  const int lm = local & 7, lnsel = local >> 3;
  const int bm = xcd * 8 + lm;
  const int sel = lnsel >> 3, bn = lnsel & 7;
  const u16* Bw = sel == 0 ? W0 : sel == 1 ? W1 : W2;
  const float* bias = sel == 0 ? b0 : sel == 1 ? b1 : b2;
  u16* outp = sel == 0 ? o0 : sel == 1 ? o1 : vt;
  const float scale = sel == 0 ? LCF : 1.0f;
  gemm_body<0>(A, Bw, bias, outp, bm, bn, MROWS, DMODEL, DMODEL, scale,
               sel == 2 ? 1 : 0, As, Bs);
}

// ---------------- flash attention (swapped QK^T, permuted K, no-max) ---------
// grid 512 (XCD-swizzled: XCD x owns bh [8x,8x+8), all 8 qt), 256 thr = 4
// waves; wave: 64 q (4 rg x 16) x 64 kv per iter. K/V fragments preloaded to
// registers once per tile and reused across all 4 rg (LDS reads q-invariant).
// LDS K-row p holds global key perm(p) = 32*(n>>1)+8*g+4*(n&1)+r (p=16n+4g+r),
// so each lane's 16 scores are exactly the keys its PV A-fragment consumes.
__global__ __launch_bounds__(256, 2) void attn_kernel(const u16* __restrict__ Qg,
                                                      const u16* __restrict__ Kg,
                                                      const u16* __restrict__ Vt,
                                                      u16* __restrict__ Og) {
  __shared__ u16 Ks[2][64 * 64];     // [key-pos][d], 8-slot XOR swizzle
  __shared__ u16 Vs[2][64 * 64];     // [d][key], 8-slot XOR swizzle

  const int t = threadIdx.x, w = t >> 6, l = t & 63;
  const int lrow = l & 15, kgrp = l >> 4;
  const int sw = lrow & 7;

  const int id = blockIdx.x;                      // 512 blocks
  const int swzid = (id & 7) * 64 + (id >> 3);    // XCD x -> 64 contiguous ids
  const int qt = swzid & 7, bh = swzid >> 3;      // bh in [8x, 8x+8)
  const int b = bh >> 4, h = bh & 15;
  const size_t base  = (size_t)b * SEQ * DMODEL + h * DK;
  const size_t vbase = (size_t)bh * DK * SEQ;
  const int r_in = l >> 3;
  const int c_in = ((l & 7) ^ r_in) * 8;

  // K staging row permutation (per-thread constants)
  int kro[2];
#pragma unroll
  for (int it = 0; it < 2; ++it) {
    const int p = (w * 2 + it) * 8 + r_in;
    const int n_ = p >> 4, g_ = (p >> 2) & 3, rr = p & 3;
    kro[it] = (n_ >> 1) * 32 + g_ * 8 + (n_ & 1) * 4 + rr;
  }

  // Q fragments (B-operand): col=q=lrow, k-octet d=kgrp*8 (+32); pre-scaled
  const int qr = qt * 256 + w * 64;
  bf16x8 aq[4][2];
#pragma unroll
  for (int rg = 0; rg < 4; ++rg) {
    const u16* qp = Qg + base + (size_t)(qr + rg * 16 + lrow) * DMODEL + kgrp * 8;
    aq[rg][0] = *(const bf16x8*)qp;
    aq[rg][1] = *(const bf16x8*)(qp + 32);
  }

  f32x4 o_acc[4][4] = {};
  float lsum[4] = {};
  const int slot0 = (kgrp ^ sw) * 8;        // kc=0 fragment slot
  const int slot1 = ((4 + kgrp) ^ sw) * 8;  // kc=1 fragment slot

#define STAGE(kt_, buf_)                                                        \
  {                                                                             \
    const int k0_ = (kt_) * 64;                                                 \
    _Pragma("unroll")                                                           \
    for (int it = 0; it < 2; ++it) {                                            \
      const int chunk = w * 2 + it;                                             \
      const int r = chunk * 8 + r_in;                                           \
      gload_lds16(Kg + base + (size_t)(k0_ + kro[it]) * DMODEL + c_in,          \
                  (char*)&Ks[buf_][0] + chunk * 1024);                          \
      gload_lds16(Vt + vbase + (size_t)r * SEQ + k0_ + c_in,                    \
                  (char*)&Vs[buf_][0] + chunk * 1024);                          \
    }                                                                           \
  }

  STAGE(0, 0);

  for (int kt = 0; kt < SEQ / 64; ++kt) {
    const int buf = kt & 1;
    __syncthreads();
    if (kt + 1 < SEQ / 64) STAGE(kt + 1, buf ^ 1);

    // K fragments: loaded ONCE, reused by all 4 rowgroups
    bf16x8 kf0[4], kf1[4];
#pragma unroll
    for (int n = 0; n < 4; ++n) {
      kf0[n] = *(const bf16x8*)&Ks[buf][(n * 16 + lrow) * 64 + slot0];
      kf1[n] = *(const bf16x8*)&Ks[buf][(n * 16 + lrow) * 64 + slot1];
    }

    // QK^T + softmax per rowgroup (sc transient per rg keeps VGPR peak low)
    bf16x8 pa[4][2];
#pragma unroll
    for (int rg = 0; rg < 4; ++rg) {
      f32x4 sc[4] = {};
      __builtin_amdgcn_s_setprio(1);
#pragma unroll
      for (int n = 0; n < 4; ++n)
        sc[n] = __builtin_amdgcn_mfma_f32_16x16x32_bf16(kf0[n], aq[rg][0], sc[n], 0, 0, 0);
#pragma unroll
      for (int n = 0; n < 4; ++n)
        sc[n] = __builtin_amdgcn_mfma_f32_16x16x32_bf16(kf1[n], aq[rg][1], sc[n], 0, 0, 0);
      __builtin_amdgcn_s_setprio(0);

      u32 pk[4][2];
      float lp = 0.0f;
#pragma unroll
      for (int n = 0; n < 4; ++n) {
        const float p0 = __builtin_amdgcn_exp2f(sc[n][0]);
        const float p1 = __builtin_amdgcn_exp2f(sc[n][1]);
        const float p2 = __builtin_amdgcn_exp2f(sc[n][2]);
        const float p3 = __builtin_amdgcn_exp2f(sc[n][3]);
        lp += (p0 + p1) + (p2 + p3);
        asm("v_cvt_pk_bf16_f32 %0, %1, %2" : "=v"(pk[n][0]) : "v"(p0), "v"(p1));
        asm("v_cvt_pk_bf16_f32 %0, %1, %2" : "=v"(pk[n][1]) : "v"(p2), "v"(p3));
      }
      lsum[rg] += lp;
      union { u32 u[4]; bf16x8 v; } f0, f1;
      f0.u[0] = pk[0][0]; f0.u[1] = pk[0][1]; f0.u[2] = pk[1][0]; f0.u[3] = pk[1][1];
      f1.u[0] = pk[2][0]; f1.u[1] = pk[2][1]; f1.u[2] = pk[3][0]; f1.u[3] = pk[3][1];
      pa[rg][0] = f0.v;
      pa[rg][1] = f1.v;
    }

    // V fragments: loaded ONCE, reused by all 4 rowgroups
    bf16x8 vf0[4], vf1[4];
#pragma unroll
    for (int n = 0; n < 4; ++n) {
      vf0[n] = *(const bf16x8*)&Vs[buf][(n * 16 + lrow) * 64 + slot0];
      vf1[n] = *(const bf16x8*)&Vs[buf][(n * 16 + lrow) * 64 + slot1];
    }

    // PV: O[64q x 64d] += P @ V
    __builtin_amdgcn_s_setprio(1);
#pragma unroll
    for (int rg = 0; rg < 4; ++rg) {
#pragma unroll
      for (int n = 0; n < 4; ++n)
        o_acc[rg][n] = __builtin_amdgcn_mfma_f32_16x16x32_bf16(pa[rg][0], vf0[n], o_acc[rg][n], 0, 0, 0);
#pragma unroll
      for (int n = 0; n < 4; ++n)
        o_acc[rg][n] = __builtin_amdgcn_mfma_f32_16x16x32_bf16(pa[rg][1], vf1[n], o_acc[rg][n], 0, 0, 0);
    }
    __builtin_amdgcn_s_setprio(0);
  }
#undef STAGE

  // epilogue: complete row sums, write O
#pragma unroll
  for (int rg = 0; rg < 4; ++rg) {
    float Lq = lsum[rg];
    Lq += __shfl_xor(Lq, 16);
    Lq += __shfl_xor(Lq, 32);                 // full sum for q = lrow
#pragma unroll
    for (int r = 0; r < 4; ++r) {
      const float inv = 1.0f / __shfl(Lq, kgrp * 4 + r);
      const int row = qr + rg * 16 + kgrp * 4 + r;
#pragma unroll
      for (int n = 0; n < 4; ++n)
        Og[base + (size_t)row * DMODEL + n * 16 + lrow] = f2bf(o_acc[rg][n][r] * inv);
    }
  }
}

// ---------------------------------------------------------------------------
extern "C" void kernel_launch(void* const* d_in, const int* in_sizes, int n_in,
                              void* d_out, int out_size, void* d_ws, size_t ws_size,
                              hipStream_t stream) {
  const float* x  = (const float*)d_in[0];
  const float* Wq = (const float*)d_in[1];
  const float* bq = (const float*)d_in[2];
  const float* Wk = (const float*)d_in[3];
  const float* bk = (const float*)d_in[4];
  const float* Wv = (const float*)d_in[5];
  const float* bv = (const float*)d_in[6];
  const float* Wo = (const float*)d_in[7];
  const float* bo = (const float*)d_in[8];
  float* out = (float*)d_out;

  const size_t XB   = (size_t)MROWS * DMODEL * 2;   // 16 MiB
  const size_t WB   = (size_t)DMODEL * DMODEL * 2;  // 2 MiB
  const size_t NEED = XB * 5 + WB * 4;
  if (ws_size < NEED) return;

  char* ws = (char*)d_ws;
  u16* xb  = (u16*)(ws);
  u16* wqb = (u16*)(ws + XB);
  u16* wkb = (u16*)(ws + XB + WB);
  u16* wvb = (u16*)(ws + XB + 2 * WB);
  u16* wob = (u16*)(ws + XB + 3 * WB);
  u16* qb  = (u16*)(ws + XB + 4 * WB);
  u16* kb  = (u16*)(ws + 2 * XB + 4 * WB);
  u16* vt  = (u16*)(ws + 3 * XB + 4 * WB);  // V^T [B,H,dk,S]
  u16* ab  = (u16*)(ws + 4 * XB + 4 * WB);

  const int NCVT = (MROWS * DMODEL / 4) + DMODEL * DMODEL;
  cvt_all<<<NCVT / 256, 256, 0, stream>>>(x, Wq, Wk, Wv, Wo, xb, wqb, wkb, wvb, wob);

  gemm_qkv<<<dim3(1536), 256, 0, stream>>>(xb, wqb, wkb, wvb,
                                           bq, bk, bv, qb, kb, vt);

  attn_kernel<<<dim3(512), 256, 0, stream>>>(qb, kb, vt, ab);

  gemm_bt_f32<<<dim3(512), 256, 0, stream>>>(ab, wob, bo, out);
}